// Round 12
// baseline (193.765 us; speedup 1.0000x reference)
//
#include <hip/hip_runtime.h>

#define NN 100000
#define EE 1600000
#define FDIM 224
#define OUTC 112

// LDS byte offsets
#define SPO 0        // A: staged scalars [32][16 slots][16B] (8KB); after s=15: x_eq (6KB)
#define HO  8192     // H [32 rows][512 cols bf16], slot-XOR (row&15)<<4 (32KB)
#define RNG 40960    // weight ring: 3 x 8KB chunks
#define WMA 65536    // Wm quarter ping (8KB)
#define WMB 73728    // Wm quarter pong (8KB)
#define LDSZ 81920   // 2 blocks/CU (160KB exactly)

typedef __attribute__((ext_vector_type(8))) short bf16x8;
typedef __attribute__((ext_vector_type(8))) unsigned short u16x8;
typedef __attribute__((ext_vector_type(4))) float f32x4;

__device__ __forceinline__ unsigned short f2bf(float f) {
  unsigned u = __builtin_bit_cast(unsigned, f);
  u = (u + 0x7FFFu + ((u >> 16) & 1u)) >> 16;   // RNE
  return (unsigned short)u;
}
__device__ __forceinline__ float bf2f(unsigned short h) {
  return __builtin_bit_cast(float, (unsigned)h << 16);
}
__device__ __forceinline__ void gl_lds16(const unsigned short* g, char* l) {
  __builtin_amdgcn_global_load_lds(
      (const __attribute__((address_space(1))) unsigned int*)g,
      (__attribute__((address_space(3))) unsigned int*)l, 16, 0, 0);
}

#define WAITV(n) do { asm volatile("s_waitcnt vmcnt(" #n ")" ::: "memory"); \
                      __builtin_amdgcn_sched_barrier(0); } while (0)
#define LGKM_BAR() do { asm volatile("s_waitcnt lgkmcnt(0)" ::: "memory"); \
                        __builtin_amdgcn_s_barrier(); } while (0)
#define KEEP(x) asm volatile("" :: "v"(x))
#define MFMA(A, B, C) __builtin_amdgcn_mfma_f32_16x16x32_bf16((A), (B), (C), 0, 0, 0)

// ---- prep kernels (unchanged, proven) -----------------------------------
__global__ void k_zero(unsigned int* p, int n) {
  int i = blockIdx.x * 256 + threadIdx.x;
  if (i < n) p[i] = 0u;
}

__global__ void k_scatter(const int* __restrict__ ei, unsigned char* __restrict__ act) {
  int e = blockIdx.x * 256 + threadIdx.x;
  if (e < EE) {
    int n = ei[e];
    if (!act[n]) act[n] = 1;
  }
}

__global__ void k_wprep(const float* __restrict__ invW1, const float* __restrict__ invW2,
                        const float* __restrict__ wembW1, const float* __restrict__ wembW2,
                        unsigned short* __restrict__ W1s, unsigned short* __restrict__ W2w,
                        unsigned short* __restrict__ W2i) {
  int i = blockIdx.x * 256 + threadIdx.x;
  if (i < 65536) {
    int c = i >> 12, j = i & 4095;
    int r128 = j >> 5, slot = (j >> 3) & 3, e = j & 7;
    int gg = slot ^ (r128 & 3);
    int n = (c >> 2) * 128 + r128;
    int k = (c & 3) * 32 + gg * 8 + e;
    float v = (n < 256) ? invW1[k * 256 + n] : wembW1[k * 256 + (n - 256)];
    W1s[i] = f2bf(v);
  } else if (i < 196608) {
    int t = i - 65536;
    int c = t >> 12, j = t & 4095;
    int r128 = j >> 5, slot = (j >> 3) & 3, e = j & 7;
    int gg = slot ^ (r128 & 3);
    int n = (c >> 3) * 128 + r128;
    int k = (c & 7) * 32 + gg * 8 + e;
    W2w[t] = f2bf(wembW2[k * 512 + n]);
  } else if (i < 212992) {
    int t = i - 196608;
    int n = t >> 8, k = t & 255;
    W2i[t] = f2bf(invW2[k * 64 + n]);
  }
}

__global__ void k_fprep(const float* __restrict__ feats,
                        unsigned short* __restrict__ SPg, unsigned short* __restrict__ XPg) {
  const int TOT = NN * 16 + NN * 12;
  for (int u = blockIdx.x * 256 + threadIdx.x; u < TOT; u += gridDim.x * 256) {
    u16x8 v;
    if (u < NN * 16) {
      int node = u >> 4, k4 = u & 15;
      const float* p = feats + (size_t)node * FDIM + k4 * 8;
      f32x4 a = *(const f32x4*)p, b = *(const f32x4*)(p + 4);
      v[0] = f2bf(a[0]); v[1] = f2bf(a[1]); v[2] = f2bf(a[2]); v[3] = f2bf(a[3]);
      v[4] = f2bf(b[0]); v[5] = f2bf(b[1]); v[6] = f2bf(b[2]); v[7] = f2bf(b[3]);
      int row = node & 31;
      *(u16x8*)(SPg + (size_t)(node >> 5) * 4096 + row * 128 + ((k4 ^ (row & 15)) * 8)) = v;
    } else {
      int t = u - NN * 16;
      int node = t / 12, j = t - node * 12;
      const float* p = feats + (size_t)node * FDIM + 128 + j * 8;
      f32x4 a = *(const f32x4*)p, b = *(const f32x4*)(p + 4);
      v[0] = f2bf(a[0]); v[1] = f2bf(a[1]); v[2] = f2bf(a[2]); v[3] = f2bf(a[3]);
      v[4] = f2bf(b[0]); v[5] = f2bf(b[1]); v[6] = f2bf(b[2]); v[7] = f2bf(b[3]);
      *(u16x8*)(XPg + (size_t)node * 96 + j * 8) = v;
    }
  }
}

// ---- fused main kernel: counted vmcnt, stage-at-top depth-2, 3-slot ring,
//      per-step lgkm-only barrier. 32 nodes/block, 512 thr, LDS 80KB. ------
__global__ __launch_bounds__(512, 4) void k_main(
    const unsigned short* __restrict__ SPg,
    const unsigned short* __restrict__ XPg,
    const unsigned short* __restrict__ Wall,   // W1s(chunks 0..15) ++ W2w(16..47)
    const unsigned short* __restrict__ W2i,
    const unsigned char* __restrict__ act,
    float* __restrict__ out) {
  __shared__ char smem[LDSZ];
  const int tid = threadIdx.x;
  const int lane = tid & 63;
  const int wv = tid >> 6;
  const int o = lane & 15;
  const int g = lane >> 4;
  const int base = blockIdx.x * 32;
  const int mtw = wv & 1, ct = wv >> 1;
  const int nloc = tid >> 4, q = tid & 15;

  const float rs128 = 0.08838834764831845f;
  const float inv16 = 0.0625f;
  const float rs32  = 0.17677669529663687f;

  // ---- prologue: compiler scalar loads, forced complete BEFORE the
  // counted DMA stream begins (stream = SPg, c0.., XPg only)
  bf16x8 b2f[8];
#pragma unroll
  for (int kk = 0; kk < 8; ++kk)
    b2f[kk] = *(const bf16x8*)(W2i + (ct * 16 + o) * 256 + kk * 32 + g * 8);
  float invm[4];
#pragma unroll
  for (int r = 0; r < 4; ++r)
    invm[r] = act[base + mtw * 16 + g * 4 + r] ? inv16 : 0.f;
  const float sC = act[base + nloc] ? rs32 : 0.f;
#pragma unroll
  for (int kk = 0; kk < 8; ++kk) KEEP((int)b2f[kk][0]);
#pragma unroll
  for (int r = 0; r < 4; ++r) KEEP(invm[r]);
  KEEP(sC);
  asm volatile("s_waitcnt vmcnt(0)" ::: "memory");

  // counted stream: SPg, c0, c1, then one chunk per step
  gl_lds16(SPg + (size_t)blockIdx.x * 4096 + wv * 512 + lane * 8, smem + SPO + wv * 1024);
  gl_lds16(Wall + 0 * 4096 + wv * 512 + lane * 8, smem + RNG + 0 * 8192 + wv * 1024);
  gl_lds16(Wall + 1 * 4096 + wv * 512 + lane * 8, smem + RNG + 1 * 8192 + wv * 1024);

  const int woff = (wv * 16 + o) * 64;
  const int wslot = (g ^ (o & 3)) << 4;
  const int hro0 = HO + o * 1024, hro1 = HO + (16 + o) * 1024;
  const int hx = o << 4;

  f32x4 acc0 = (f32x4){0.f, 0.f, 0.f, 0.f};
  f32x4 acc1 = (f32x4){0.f, 0.f, 0.f, 0.f};
  f32x4 acc2 = (f32x4){0.f, 0.f, 0.f, 0.f};
  float eq0 = 0.f, eq1 = 0.f, eq2 = 0.f;

  // ================= A phase: chunks 0..15 ==============================
#pragma unroll
  for (int s = 0; s < 16; ++s) {
    const int ks = s & 3, QQ = s >> 2;
    // stage-at-top: c_{s+2} -> slot (s+2)%3 (never the slot read this step;
    // victim slot's reads were lgkm-drained at the previous step's barrier)
    gl_lds16(Wall + (size_t)(s + 2) * 4096 + wv * 512 + lane * 8,
             smem + RNG + ((s + 2) % 3) * 8192 + wv * 1024);
    WAITV(2);                                  // c_s landed (in-order vmcnt)
    if (s == 0) __builtin_amdgcn_s_barrier();  // all waves' SPg landed
    {
      const int aslot = ((ks * 4 + g) ^ o) << 4;
      bf16x8 a0 = *(const bf16x8*)(smem + SPO + o * 256 + aslot);
      bf16x8 a1 = *(const bf16x8*)(smem + SPO + (16 + o) * 256 + aslot);
      bf16x8 b = *(const bf16x8*)(smem + RNG + (s % 3) * 8192 + woff + wslot);
      acc0 = MFMA(a0, b, acc0);
      acc1 = MFMA(a1, b, acc1);
    }
    if (s >= 8) {                              // interleaved inv GEMM
      const int kk = s - 8;
      bf16x8 hi = *(const bf16x8*)(smem + HO + (mtw * 16 + o) * 1024 +
                                   ((kk * 64 + g * 16) ^ hx));
      acc2 = MFMA(hi, b2f[kk], acc2);
    }
    if (ks == 3) {                             // silu -> H for this QQ
#pragma unroll
      for (int mt = 0; mt < 2; ++mt) {
        f32x4 a = mt ? acc1 : acc0;
#pragma unroll
        for (int r = 0; r < 4; ++r) {
          int row = mt * 16 + g * 4 + r;
          int col = QQ * 128 + wv * 16 + o;
          float v = a[r] * rs128;
          float h = v / (1.f + __expf(-v));
          *(unsigned short*)(smem + HO + row * 1024 + ((col * 2) ^ ((row & 15) << 4))) = f2bf(h);
        }
      }
      acc0 = (f32x4){0.f, 0.f, 0.f, 0.f};
      acc1 = (f32x4){0.f, 0.f, 0.f, 0.f};
    }
    LGKM_BAR();                                // ds drained + barrier; vmcnt in flight
    if (s == 15) {
      // SPO is now free (all waves' A-frag reads drained at this barrier).
      // Uniform streams: every wave issues exactly one XPg DMA; waves 6,7
      // duplicate segments 0,1 (identical bytes -> benign write-write).
      const int seg = (wv < 6) ? wv : (wv - 6);
      gl_lds16(XPg + (size_t)blockIdx.x * 3072 + seg * 512 + lane * 8,
               smem + SPO + seg * 1024);
    }
  }

  // ================= B phase: chunks 16..47 =============================
#pragma unroll
  for (int s = 16; s < 48; ++s) {
    const int t = s - 16, kk = t & 7, QQ = t >> 3;
    if (s + 2 <= 47)
      gl_lds16(Wall + (size_t)(s + 2) * 4096 + wv * 512 + lane * 8,
               smem + RNG + ((s + 2) % 3) * 8192 + wv * 1024);
    // waits: stream ... c16, c17, XPg, c18, c19, ...
    if (s == 16 || s == 17) WAITV(3);
    else if (s == 18) WAITV(2);                // drains XPg too
    else if (s <= 45) WAITV(2);
    else if (s == 46) WAITV(1);
    else WAITV(0);
    {
      const int hb = 512 + kk * 64 + g * 16;
      bf16x8 h0 = *(const bf16x8*)(smem + hro0 + (hb ^ hx));
      bf16x8 h1 = *(const bf16x8*)(smem + hro1 + (hb ^ hx));
      bf16x8 b = *(const bf16x8*)(smem + RNG + (s % 3) * 8192 + woff + wslot);
      acc0 = MFMA(h0, b, acc0);
      acc1 = MFMA(h1, b, acc1);
    }
    if (t >= 8) {                              // phase-C slice, prev quarter
      const int Qp = QQ - 1, il = kk;
      const int wmoff = (Qp & 1) ? WMB : WMA;
      unsigned short w = *(const unsigned short*)(
          smem + wmoff + nloc * 256 + (((il * 16 + q) * 2) ^ ((nloc & 7) << 5)));
      float wf = bf2f(w);
      const int xb = nloc * 192 + (Qp * 24 + il * 3) * 2;
      eq0 += bf2f(*(const unsigned short*)(smem + SPO + xb + 0)) * wf;
      eq1 += bf2f(*(const unsigned short*)(smem + SPO + xb + 2)) * wf;
      eq2 += bf2f(*(const unsigned short*)(smem + SPO + xb + 4)) * wf;
    }
    if (kk == 7) {                             // Wm quarter write
      const int wmoff = (QQ & 1) ? WMB : WMA;
#pragma unroll
      for (int mt = 0; mt < 2; ++mt) {
        f32x4 a = mt ? acc1 : acc0;
#pragma unroll
        for (int r = 0; r < 4; ++r) {
          int n = mt * 16 + g * 4 + r;
          int lc = wv * 16 + o;
          *(unsigned short*)(smem + wmoff + n * 256 + ((lc * 2) ^ ((n & 7) << 5))) =
              f2bf(a[r] * inv16);
        }
      }
      acc0 = (f32x4){0.f, 0.f, 0.f, 0.f};
      acc1 = (f32x4){0.f, 0.f, 0.f, 0.f};
    }
    LGKM_BAR();
  }

  // ---- epilogue: final quarter (Qp=3, in WMB) + all global stores ------
#pragma unroll
  for (int il = 0; il < 8; ++il) {
    unsigned short w = *(const unsigned short*)(
        smem + WMB + nloc * 256 + (((il * 16 + q) * 2) ^ ((nloc & 7) << 5)));
    float wf = bf2f(w);
    const int xb = nloc * 192 + (72 + il * 3) * 2;
    eq0 += bf2f(*(const unsigned short*)(smem + SPO + xb + 0)) * wf;
    eq1 += bf2f(*(const unsigned short*)(smem + SPO + xb + 2)) * wf;
    eq2 += bf2f(*(const unsigned short*)(smem + SPO + xb + 4)) * wf;
  }

#pragma unroll
  for (int r = 0; r < 4; ++r) {
    int node = base + mtw * 16 + g * 4 + r;
    out[(size_t)node * OUTC + ct * 16 + o] = acc2[r] * invm[r];
  }
  float* op = out + (size_t)(base + nloc) * OUTC + 64 + q * 3;
  op[0] = eq0 * sC;
  op[1] = eq1 * sC;
  op[2] = eq2 * sC;
}

// ---- launch ------------------------------------------------------------
extern "C" void kernel_launch(void* const* d_in, const int* in_sizes, int n_in,
                              void* d_out, int out_size, void* d_ws, size_t ws_size,
                              hipStream_t stream) {
  const float* feats = (const float*)d_in[0];
  const int* ei = (const int*)d_in[1];
  const float* invW1 = (const float*)d_in[2];
  const float* invW2 = (const float*)d_in[3];
  const float* wembW1 = (const float*)d_in[4];
  const float* wembW2 = (const float*)d_in[5];
  float* out = (float*)d_out;

  char* ws = (char*)d_ws;
  unsigned short* W1s = (unsigned short*)(ws);                    // 131072 B (chunks 0..15)
  unsigned short* W2w = (unsigned short*)(ws + 131072);           // 262144 B (chunks 16..47)
  unsigned short* W2i = (unsigned short*)(ws + 393216);           // 32768 B
  unsigned char* act  = (unsigned char*)(ws + 425984);            // 100096 B
  unsigned short* SPg = (unsigned short*)(ws + 526080);           // 25.6 MB
  unsigned short* XPg = (unsigned short*)(ws + 26126080);         // 19.2 MB

  k_zero<<<98, 256, 0, stream>>>((unsigned int*)act, 25024);
  k_scatter<<<6250, 256, 0, stream>>>(ei, act);
  k_wprep<<<832, 256, 0, stream>>>(invW1, invW2, wembW1, wembW2, W1s, W2w, W2i);
  k_fprep<<<2048, 256, 0, stream>>>(feats, SPg, XPg);
  k_main<<<3125, 512, 0, stream>>>(SPg, XPg, W1s, W2i, act, out);
}

// Round 14
// 185.735 us; speedup vs baseline: 1.0432x; 1.0432x over previous
//
#include <hip/hip_runtime.h>

#define NN 100000
#define EE 1600000
#define FDIM 224
#define OUTC 112

// LDS byte offsets
#define SPO 0        // A: staged scalars [32][16 slots][16B] (8KB); after s=15: x_eq (6KB)
#define HO  8192     // H [32 rows][512 cols bf16], slot-XOR (row&15)<<4 (32KB)
#define RNG 40960    // weight ring: 3 x 8KB chunks
#define WMA 65536    // Wm quarter ping (8KB)
#define WMB 73728    // Wm quarter pong (8KB)
#define LDSZ 81920   // 2 blocks/CU (160KB exactly)

typedef __attribute__((ext_vector_type(8))) short bf16x8;
typedef __attribute__((ext_vector_type(8))) unsigned short u16x8;
typedef __attribute__((ext_vector_type(4))) float f32x4;

__device__ __forceinline__ unsigned short f2bf(float f) {
  unsigned u = __builtin_bit_cast(unsigned, f);
  u = (u + 0x7FFFu + ((u >> 16) & 1u)) >> 16;   // RNE
  return (unsigned short)u;
}
__device__ __forceinline__ float bf2f(unsigned short h) {
  return __builtin_bit_cast(float, (unsigned)h << 16);
}
__device__ __forceinline__ void gl_lds16(const unsigned short* g, char* l) {
  __builtin_amdgcn_global_load_lds(
      (const __attribute__((address_space(1))) unsigned int*)g,
      (__attribute__((address_space(3))) unsigned int*)l, 16, 0, 0);
}

#define WAITV(n) do { asm volatile("s_waitcnt vmcnt(" #n ")" ::: "memory"); \
                      __builtin_amdgcn_sched_barrier(0); } while (0)
#define LGKM0() asm volatile("s_waitcnt lgkmcnt(0)" ::: "memory")
#define LGKM_BAR() do { asm volatile("s_waitcnt lgkmcnt(0)" ::: "memory"); \
                        __builtin_amdgcn_s_barrier(); } while (0)
#define KEEP(x) asm volatile("" :: "v"(x))
#define MFMA(A, B, C) __builtin_amdgcn_mfma_f32_16x16x32_bf16((A), (B), (C), 0, 0, 0)

// ---- prep kernels (unchanged, proven) -----------------------------------
__global__ void k_zero(unsigned int* p, int n) {
  int i = blockIdx.x * 256 + threadIdx.x;
  if (i < n) p[i] = 0u;
}

__global__ void k_scatter(const int* __restrict__ ei, unsigned char* __restrict__ act) {
  int e = blockIdx.x * 256 + threadIdx.x;
  if (e < EE) {
    int n = ei[e];
    if (!act[n]) act[n] = 1;
  }
}

__global__ void k_wprep(const float* __restrict__ invW1, const float* __restrict__ invW2,
                        const float* __restrict__ wembW1, const float* __restrict__ wembW2,
                        unsigned short* __restrict__ W1s, unsigned short* __restrict__ W2w,
                        unsigned short* __restrict__ W2i) {
  int i = blockIdx.x * 256 + threadIdx.x;
  if (i < 65536) {
    int c = i >> 12, j = i & 4095;
    int r128 = j >> 5, slot = (j >> 3) & 3, e = j & 7;
    int gg = slot ^ (r128 & 3);
    int n = (c >> 2) * 128 + r128;
    int k = (c & 3) * 32 + gg * 8 + e;
    float v = (n < 256) ? invW1[k * 256 + n] : wembW1[k * 256 + (n - 256)];
    W1s[i] = f2bf(v);
  } else if (i < 196608) {
    int t = i - 65536;
    int c = t >> 12, j = t & 4095;
    int r128 = j >> 5, slot = (j >> 3) & 3, e = j & 7;
    int gg = slot ^ (r128 & 3);
    int n = (c >> 3) * 128 + r128;
    int k = (c & 7) * 32 + gg * 8 + e;
    W2w[t] = f2bf(wembW2[k * 512 + n]);
  } else if (i < 212992) {
    int t = i - 196608;
    int n = t >> 8, k = t & 255;
    W2i[t] = f2bf(invW2[k * 64 + n]);
  }
}

__global__ void k_fprep(const float* __restrict__ feats,
                        unsigned short* __restrict__ SPg, unsigned short* __restrict__ XPg) {
  const int TOT = NN * 16 + NN * 12;
  for (int u = blockIdx.x * 256 + threadIdx.x; u < TOT; u += gridDim.x * 256) {
    u16x8 v;
    if (u < NN * 16) {
      int node = u >> 4, k4 = u & 15;
      const float* p = feats + (size_t)node * FDIM + k4 * 8;
      f32x4 a = *(const f32x4*)p, b = *(const f32x4*)(p + 4);
      v[0] = f2bf(a[0]); v[1] = f2bf(a[1]); v[2] = f2bf(a[2]); v[3] = f2bf(a[3]);
      v[4] = f2bf(b[0]); v[5] = f2bf(b[1]); v[6] = f2bf(b[2]); v[7] = f2bf(b[3]);
      int row = node & 31;
      *(u16x8*)(SPg + (size_t)(node >> 5) * 4096 + row * 128 + ((k4 ^ (row & 15)) * 8)) = v;
    } else {
      int t = u - NN * 16;
      int node = t / 12, j = t - node * 12;
      const float* p = feats + (size_t)node * FDIM + 128 + j * 8;
      f32x4 a = *(const f32x4*)p, b = *(const f32x4*)(p + 4);
      v[0] = f2bf(a[0]); v[1] = f2bf(a[1]); v[2] = f2bf(a[2]); v[3] = f2bf(a[3]);
      v[4] = f2bf(b[0]); v[5] = f2bf(b[1]); v[6] = f2bf(b[2]); v[7] = f2bf(b[3]);
      *(u16x8*)(XPg + (size_t)node * 96 + j * 8) = v;
    }
  }
}

// ---- fused main kernel: 7 barriers + per-step lgkm drain before restage.
// Ring safety: lgkmcnt(0) before each DMA stage guarantees the overwritten
// slot's ds_reads completed (rule-18-proof regardless of MFMA sinking).
// 32 nodes/block, 512 thr (8 waves), LDS 80KB -> 2 blocks/CU. Grid 3125.
__global__ __launch_bounds__(512, 4) void k_main(
    const unsigned short* __restrict__ SPg,
    const unsigned short* __restrict__ XPg,
    const unsigned short* __restrict__ Wall,   // W1s(chunks 0..15) ++ W2w(16..47)
    const unsigned short* __restrict__ W2i,
    const unsigned char* __restrict__ act,
    float* __restrict__ out) {
  __shared__ char smem[LDSZ];
  const int tid = threadIdx.x;
  const int lane = tid & 63;
  const int wv = tid >> 6;
  const int o = lane & 15;
  const int g = lane >> 4;
  const int base = blockIdx.x * 32;
  const int mtw = wv & 1, ct = wv >> 1;
  const int nloc = tid >> 4, q = tid & 15;

  const float rs128 = 0.08838834764831845f;
  const float inv16 = 0.0625f;
  const float rs32  = 0.17677669529663687f;

  // ---- prologue: compiler scalar loads forced complete BEFORE the
  // counted DMA stream begins (stream = SPg, chunks, XPg only)
  bf16x8 b2f[8];
#pragma unroll
  for (int kk = 0; kk < 8; ++kk)
    b2f[kk] = *(const bf16x8*)(W2i + (ct * 16 + o) * 256 + kk * 32 + g * 8);
  float invm[4];
#pragma unroll
  for (int r = 0; r < 4; ++r)
    invm[r] = act[base + mtw * 16 + g * 4 + r] ? inv16 : 0.f;
  const float sC = act[base + nloc] ? rs32 : 0.f;
#pragma unroll
  for (int kk = 0; kk < 8; ++kk) KEEP((int)b2f[kk][0]);
#pragma unroll
  for (int r = 0; r < 4; ++r) KEEP(invm[r]);
  KEEP(sC);
  asm volatile("s_waitcnt vmcnt(0)" ::: "memory");

  // counted stream: SPg, c0, c1, then one chunk per step (stage-at-top)
  gl_lds16(SPg + (size_t)blockIdx.x * 4096 + wv * 512 + lane * 8, smem + SPO + wv * 1024);
  gl_lds16(Wall + 0 * 4096 + wv * 512 + lane * 8, smem + RNG + 0 * 8192 + wv * 1024);
  gl_lds16(Wall + 1 * 4096 + wv * 512 + lane * 8, smem + RNG + 1 * 8192 + wv * 1024);

  const int woff = (wv * 16 + o) * 64;
  const int wslot = (g ^ (o & 3)) << 4;
  const int hro0 = HO + o * 1024, hro1 = HO + (16 + o) * 1024;
  const int hx = o << 4;

  f32x4 acc0 = (f32x4){0.f, 0.f, 0.f, 0.f};
  f32x4 acc1 = (f32x4){0.f, 0.f, 0.f, 0.f};
  f32x4 acc2 = (f32x4){0.f, 0.f, 0.f, 0.f};
  float eq0 = 0.f, eq1 = 0.f, eq2 = 0.f;

  // ================= A phase: chunks 0..15 ==============================
#pragma unroll
  for (int s = 0; s < 16; ++s) {
    const int ks = s & 3, QQ = s >> 2;
    // ring-slot WAR guard: all prior ds_reads (incl. victim slot's) complete
    LGKM0();
    gl_lds16(Wall + (size_t)(s + 2) * 4096 + wv * 512 + lane * 8,
             smem + RNG + ((s + 2) % 3) * 8192 + wv * 1024);
    WAITV(2);                                  // c_s landed (in-order vmcnt)
    if (s == 0) __builtin_amdgcn_s_barrier();  // all waves' SPg landed
    {
      const int aslot = ((ks * 4 + g) ^ o) << 4;
      bf16x8 a0 = *(const bf16x8*)(smem + SPO + o * 256 + aslot);
      bf16x8 a1 = *(const bf16x8*)(smem + SPO + (16 + o) * 256 + aslot);
      bf16x8 b = *(const bf16x8*)(smem + RNG + (s % 3) * 8192 + woff + wslot);
      acc0 = MFMA(a0, b, acc0);
      acc1 = MFMA(a1, b, acc1);
    }
    if (s >= 8) {                              // interleaved inv GEMM
      const int kk = s - 8;
      bf16x8 hi = *(const bf16x8*)(smem + HO + (mtw * 16 + o) * 1024 +
                                   ((kk * 64 + g * 16) ^ hx));
      acc2 = MFMA(hi, b2f[kk], acc2);
    }
    if (ks == 3) {                             // silu -> H for this QQ
#pragma unroll
      for (int mt = 0; mt < 2; ++mt) {
        f32x4 a = mt ? acc1 : acc0;
#pragma unroll
        for (int r = 0; r < 4; ++r) {
          int row = mt * 16 + g * 4 + r;
          int col = QQ * 128 + wv * 16 + o;
          float v = a[r] * rs128;
          float h = v / (1.f + __expf(-v));
          *(unsigned short*)(smem + HO + row * 1024 + ((col * 2) ^ ((row & 15) << 4))) = f2bf(h);
        }
      }
      acc0 = (f32x4){0.f, 0.f, 0.f, 0.f};
      acc1 = (f32x4){0.f, 0.f, 0.f, 0.f};
    }
    if (s == 7) LGKM_BAR();                    // publish H cols 0..255
    if (s == 15) {
      LGKM_BAR();                              // publish H cols 256..511; SPO free
      const int seg = (wv < 6) ? wv : (wv - 6);
      gl_lds16(XPg + (size_t)blockIdx.x * 3072 + seg * 512 + lane * 8,
               smem + SPO + seg * 1024);
    }
  }

  // ================= B phase: chunks 16..47 =============================
#pragma unroll
  for (int s = 16; s < 48; ++s) {
    const int t = s - 16, kk = t & 7, QQ = t >> 3;
    if (s + 2 <= 47) {
      LGKM0();                                 // ring-slot WAR guard
      gl_lds16(Wall + (size_t)(s + 2) * 4096 + wv * 512 + lane * 8,
               smem + RNG + ((s + 2) % 3) * 8192 + wv * 1024);
    }
    // stream: ..., c17, XPg, c18, ... (XPg drained by s=18's WAITV(2))
    if (s == 16 || s == 17) WAITV(3);
    else if (s <= 45) WAITV(2);
    else if (s == 46) WAITV(1);
    else WAITV(0);
    {
      const int hb = 512 + kk * 64 + g * 16;
      bf16x8 h0 = *(const bf16x8*)(smem + hro0 + (hb ^ hx));
      bf16x8 h1 = *(const bf16x8*)(smem + hro1 + (hb ^ hx));
      bf16x8 b = *(const bf16x8*)(smem + RNG + (s % 3) * 8192 + woff + wslot);
      acc0 = MFMA(h0, b, acc0);
      acc1 = MFMA(h1, b, acc1);
    }
    if (t >= 8) {                              // phase-C slice, prev quarter
      const int Qp = QQ - 1, il = kk;
      const int wmoff = (Qp & 1) ? WMB : WMA;
      unsigned short w = *(const unsigned short*)(
          smem + wmoff + nloc * 256 + (((il * 16 + q) * 2) ^ ((nloc & 7) << 5)));
      float wf = bf2f(w);
      const int xb = nloc * 192 + (Qp * 24 + il * 3) * 2;
      eq0 += bf2f(*(const unsigned short*)(smem + SPO + xb + 0)) * wf;
      eq1 += bf2f(*(const unsigned short*)(smem + SPO + xb + 2)) * wf;
      eq2 += bf2f(*(const unsigned short*)(smem + SPO + xb + 4)) * wf;
    }
    if (kk == 7) {                             // Wm quarter write
      const int wmoff = (QQ & 1) ? WMB : WMA;
#pragma unroll
      for (int mt = 0; mt < 2; ++mt) {
        f32x4 a = mt ? acc1 : acc0;
#pragma unroll
        for (int r = 0; r < 4; ++r) {
          int n = mt * 16 + g * 4 + r;
          int lc = wv * 16 + o;
          *(unsigned short*)(smem + wmoff + n * 256 + ((lc * 2) ^ ((n & 7) << 5))) =
              f2bf(a[r] * inv16);
        }
      }
      acc0 = (f32x4){0.f, 0.f, 0.f, 0.f};
      acc1 = (f32x4){0.f, 0.f, 0.f, 0.f};
      LGKM_BAR();                              // publish Wm quarter (s=23,31,39,47)
    }
  }

  // ---- epilogue: final quarter (Qp=3, in WMB) + all global stores ------
#pragma unroll
  for (int il = 0; il < 8; ++il) {
    unsigned short w = *(const unsigned short*)(
        smem + WMB + nloc * 256 + (((il * 16 + q) * 2) ^ ((nloc & 7) << 5)));
    float wf = bf2f(w);
    const int xb = nloc * 192 + (72 + il * 3) * 2;
    eq0 += bf2f(*(const unsigned short*)(smem + SPO + xb + 0)) * wf;
    eq1 += bf2f(*(const unsigned short*)(smem + SPO + xb + 2)) * wf;
    eq2 += bf2f(*(const unsigned short*)(smem + SPO + xb + 4)) * wf;
  }

#pragma unroll
  for (int r = 0; r < 4; ++r) {
    int node = base + mtw * 16 + g * 4 + r;
    out[(size_t)node * OUTC + ct * 16 + o] = acc2[r] * invm[r];
  }
  float* op = out + (size_t)(base + nloc) * OUTC + 64 + q * 3;
  op[0] = eq0 * sC;
  op[1] = eq1 * sC;
  op[2] = eq2 * sC;
}

// ---- launch ------------------------------------------------------------
extern "C" void kernel_launch(void* const* d_in, const int* in_sizes, int n_in,
                              void* d_out, int out_size, void* d_ws, size_t ws_size,
                              hipStream_t stream) {
  const float* feats = (const float*)d_in[0];
  const int* ei = (const int*)d_in[1];
  const float* invW1 = (const float*)d_in[2];
  const float* invW2 = (const float*)d_in[3];
  const float* wembW1 = (const float*)d_in[4];
  const float* wembW2 = (const float*)d_in[5];
  float* out = (float*)d_out;

  char* ws = (char*)d_ws;
  unsigned short* W1s = (unsigned short*)(ws);                    // 131072 B (chunks 0..15)
  unsigned short* W2w = (unsigned short*)(ws + 131072);           // 262144 B (chunks 16..47)
  unsigned short* W2i = (unsigned short*)(ws + 393216);           // 32768 B
  unsigned char* act  = (unsigned char*)(ws + 425984);            // 100096 B
  unsigned short* SPg = (unsigned short*)(ws + 526080);           // 25.6 MB
  unsigned short* XPg = (unsigned short*)(ws + 26126080);         // 19.2 MB

  k_zero<<<98, 256, 0, stream>>>((unsigned int*)act, 25024);
  k_scatter<<<6250, 256, 0, stream>>>(ei, act);
  k_wprep<<<832, 256, 0, stream>>>(invW1, invW2, wembW1, wembW2, W1s, W2w, W2i);
  k_fprep<<<2048, 256, 0, stream>>>(feats, SPg, XPg);
  k_main<<<3125, 512, 0, stream>>>(SPg, XPg, W1s, W2i, act, out);
}

// Round 15
// 152.704 us; speedup vs baseline: 1.2689x; 1.2163x over previous
//
#include <hip/hip_runtime.h>

#define NN 100000
#define EE 1600000
#define FDIM 224
#define OUTC 112

// LDS byte offsets
#define SPO 0        // A: staged scalars [32][16 slots][16B] (8KB); after s=15: x_eq (6KB)
#define HO  8192     // H [32 rows][512 cols bf16], slot-XOR (row&15)<<4 (32KB)
#define RNG 40960    // weight ring: 3 x 8KB chunks
#define WMA 65536    // Wm quarter ping (8KB)
#define WMB 73728    // Wm quarter pong (8KB)
#define LDSZ 81920   // 2 blocks/CU (160KB exactly)

typedef __attribute__((ext_vector_type(8))) short bf16x8;
typedef __attribute__((ext_vector_type(8))) unsigned short u16x8;
typedef __attribute__((ext_vector_type(4))) float f32x4;
typedef __attribute__((ext_vector_type(2))) float f32x2;
typedef __attribute__((ext_vector_type(4))) unsigned int u32x4;
typedef __attribute__((ext_vector_type(4))) int i32x4;

__device__ __forceinline__ unsigned short f2bf(float f) {
  unsigned u = __builtin_bit_cast(unsigned, f);
  u = (u + 0x7FFFu + ((u >> 16) & 1u)) >> 16;   // RNE
  return (unsigned short)u;
}
__device__ __forceinline__ float bf2f(unsigned short h) {
  return __builtin_bit_cast(float, (unsigned)h << 16);
}
__device__ __forceinline__ unsigned cvtpk(float lo, float hi) {
  unsigned d;
  asm("v_cvt_pk_bf16_f32 %0, %1, %2" : "=v"(d) : "v"(lo), "v"(hi));
  return d;
}
__device__ __forceinline__ float fast_exp2(float t) {
  float e; asm("v_exp_f32 %0, %1" : "=v"(e) : "v"(t)); return e;
}
__device__ __forceinline__ float fast_rcp(float x) {
  float r; asm("v_rcp_f32 %0, %1" : "=v"(r) : "v"(x)); return r;
}
// silu(a * rs128)
__device__ __forceinline__ float silu_rs(float a) {
  float v = a * 0.08838834764831845f;
  float e = fast_exp2(v * -1.442695041f);
  return v * fast_rcp(1.f + e);
}
__device__ __forceinline__ void gl_lds16(const unsigned short* g, char* l) {
  __builtin_amdgcn_global_load_lds(
      (const __attribute__((address_space(1))) unsigned int*)g,
      (__attribute__((address_space(3))) unsigned int*)l, 16, 0, 0);
}

#define WAITV(n) do { asm volatile("s_waitcnt vmcnt(" #n ")" ::: "memory"); \
                      __builtin_amdgcn_sched_barrier(0); } while (0)
#define LGKM0() asm volatile("s_waitcnt lgkmcnt(0)" ::: "memory")
#define LGKM_BAR() do { asm volatile("s_waitcnt lgkmcnt(0)" ::: "memory"); \
                        __builtin_amdgcn_s_barrier(); } while (0)
#define KEEP(x) asm volatile("" :: "v"(x))
#define MFMA(A, B, C) __builtin_amdgcn_mfma_f32_16x16x32_bf16((A), (B), (C), 0, 0, 0)

// ---- prep kernels -------------------------------------------------------
__global__ void k_zero(unsigned int* p, int n) {
  int i = blockIdx.x * 256 + threadIdx.x;
  if (i < n) p[i] = 0u;
}

// int4-vectorized test-and-set
__global__ void k_scatter(const int* __restrict__ ei, unsigned char* __restrict__ act) {
  int e4 = blockIdx.x * 256 + threadIdx.x;
  if (e4 < EE / 4) {
    i32x4 v = *(const i32x4*)(ei + e4 * 4);
#pragma unroll
    for (int j = 0; j < 4; ++j) {
      int n = v[j];
      if (!act[n]) act[n] = 1;
    }
  }
}

__global__ void k_wprep(const float* __restrict__ invW1, const float* __restrict__ invW2,
                        const float* __restrict__ wembW1, const float* __restrict__ wembW2,
                        unsigned short* __restrict__ W1s, unsigned short* __restrict__ W2w,
                        unsigned short* __restrict__ W2i) {
  int i = blockIdx.x * 256 + threadIdx.x;
  if (i < 65536) {
    int c = i >> 12, j = i & 4095;
    int r128 = j >> 5, slot = (j >> 3) & 3, e = j & 7;
    int gg = slot ^ (r128 & 3);
    int n = (c >> 2) * 128 + r128;
    int k = (c & 3) * 32 + gg * 8 + e;
    float v = (n < 256) ? invW1[k * 256 + n] : wembW1[k * 256 + (n - 256)];
    W1s[i] = f2bf(v);
  } else if (i < 196608) {
    int t = i - 65536;
    int c = t >> 12, j = t & 4095;
    int r128 = j >> 5, slot = (j >> 3) & 3, e = j & 7;
    int gg = slot ^ (r128 & 3);
    int n = (c >> 3) * 128 + r128;
    int k = (c & 7) * 32 + gg * 8 + e;
    W2w[t] = f2bf(wembW2[k * 512 + n]);
  } else if (i < 212992) {
    int t = i - 196608;
    int n = t >> 8, k = t & 255;
    W2i[t] = f2bf(invW2[k * 64 + n]);
  }
}

// ---- fused main kernel: r14 core; in-kernel feature staging; VALU diet --
// 32 nodes/block, 512 thr (8 waves), LDS 80KB -> 2 blocks/CU. Grid 3125.
__global__ __launch_bounds__(512, 4) void k_main(
    const float* __restrict__ feats,
    const unsigned short* __restrict__ Wall,   // W1s(chunks 0..15) ++ W2w(16..47)
    const unsigned short* __restrict__ W2i,
    const unsigned char* __restrict__ act,
    float* __restrict__ out) {
  __shared__ char smem[LDSZ];
  const int tid = threadIdx.x;
  const int lane = tid & 63;
  const int wv = tid >> 6;
  const int o = lane & 15;
  const int g = lane >> 4;
  const int base = blockIdx.x * 32;
  const int mtw = wv & 1, ct = wv >> 1;
  const int nloc = tid >> 4, q = tid & 15;

  const float inv16 = 0.0625f;
  const float rs32  = 0.17677669529663687f;

  // ---- prologue: all scalar/feature loads issued, converted, staged, and
  // drained BEFORE the counted DMA stream begins (stream = chunks only)
  const int srow = tid >> 4, sj = tid & 15;
  const float* sp = feats + (size_t)(base + srow) * FDIM + sj * 8;
  f32x4 s0 = *(const f32x4*)sp;
  f32x4 s1 = *(const f32x4*)(sp + 4);
  const float* xp = feats + (size_t)(base + srow) * FDIM + 128 + sj * 6;
  f32x2 xa = *(const f32x2*)xp;
  f32x2 xbv = *(const f32x2*)(xp + 2);
  f32x2 xc = *(const f32x2*)(xp + 4);

  bf16x8 b2f[8];
#pragma unroll
  for (int kk = 0; kk < 8; ++kk)
    b2f[kk] = *(const bf16x8*)(W2i + (ct * 16 + o) * 256 + kk * 32 + g * 8);
  float invm[4];
#pragma unroll
  for (int r = 0; r < 4; ++r)
    invm[r] = act[base + mtw * 16 + g * 4 + r] ? inv16 : 0.f;
  const float sC = act[base + nloc] ? rs32 : 0.f;

  // scalars -> SPO (bf16, pre-swizzled), published below
  {
    unsigned w0 = cvtpk(s0[0], s0[1]);
    unsigned w1 = cvtpk(s0[2], s0[3]);
    unsigned w2 = cvtpk(s1[0], s1[1]);
    unsigned w3 = cvtpk(s1[2], s1[3]);
    *(u32x4*)(smem + SPO + srow * 256 + ((sj ^ (srow & 15)) << 4)) =
        (u32x4){w0, w1, w2, w3};
  }
#pragma unroll
  for (int kk = 0; kk < 8; ++kk) KEEP((int)b2f[kk][0]);
#pragma unroll
  for (int r = 0; r < 4; ++r) KEEP(invm[r]);
  KEEP(sC);
  KEEP(xa[0]); KEEP(xa[1]); KEEP(xbv[0]); KEEP(xbv[1]); KEEP(xc[0]); KEEP(xc[1]);
  asm volatile("s_waitcnt vmcnt(0)" ::: "memory");
  LGKM_BAR();                                  // SPO published to all waves

  // counted stream: c0, c1, then one chunk per step (stage-at-top)
  gl_lds16(Wall + 0 * 4096 + wv * 512 + lane * 8, smem + RNG + 0 * 8192 + wv * 1024);
  gl_lds16(Wall + 1 * 4096 + wv * 512 + lane * 8, smem + RNG + 1 * 8192 + wv * 1024);

  const int woff = (wv * 16 + o) * 64;
  const int wslot = (g ^ (o & 3)) << 4;
  const int hro0 = HO + o * 1024, hro1 = HO + (16 + o) * 1024;
  const int hx = o << 4;

  f32x4 acc0 = (f32x4){0.f, 0.f, 0.f, 0.f};
  f32x4 acc1 = (f32x4){0.f, 0.f, 0.f, 0.f};
  f32x4 acc2 = (f32x4){0.f, 0.f, 0.f, 0.f};
  float eq0 = 0.f, eq1 = 0.f, eq2 = 0.f;

  // ================= A phase: chunks 0..15 ==============================
#pragma unroll
  for (int s = 0; s < 16; ++s) {
    const int ks = s & 3, QQ = s >> 2;
    LGKM0();                                   // ring-slot WAR guard
    gl_lds16(Wall + (size_t)(s + 2) * 4096 + wv * 512 + lane * 8,
             smem + RNG + ((s + 2) % 3) * 8192 + wv * 1024);
    WAITV(2);                                  // c_s landed (in-order vmcnt)
    __builtin_amdgcn_s_setprio(1);
    {
      const int aslot = ((ks * 4 + g) ^ o) << 4;
      bf16x8 a0 = *(const bf16x8*)(smem + SPO + o * 256 + aslot);
      bf16x8 a1 = *(const bf16x8*)(smem + SPO + (16 + o) * 256 + aslot);
      bf16x8 b = *(const bf16x8*)(smem + RNG + (s % 3) * 8192 + woff + wslot);
      acc0 = MFMA(a0, b, acc0);
      acc1 = MFMA(a1, b, acc1);
    }
    if (s >= 8) {                              // interleaved inv GEMM
      const int kk = s - 8;
      bf16x8 hi = *(const bf16x8*)(smem + HO + (mtw * 16 + o) * 1024 +
                                   ((kk * 64 + g * 16) ^ hx));
      acc2 = MFMA(hi, b2f[kk], acc2);
    }
    __builtin_amdgcn_s_setprio(0);
    if (ks == 3) {                             // silu -> H for this QQ
#pragma unroll
      for (int mt = 0; mt < 2; ++mt) {
        f32x4 a = mt ? acc1 : acc0;
        const int col = QQ * 128 + wv * 16 + o;
#pragma unroll
        for (int rp = 0; rp < 2; ++rp) {
          float h0 = silu_rs(a[rp * 2]);
          float h1 = silu_rs(a[rp * 2 + 1]);
          unsigned w = cvtpk(h0, h1);
          int row0 = mt * 16 + g * 4 + rp * 2;
          *(unsigned short*)(smem + HO + row0 * 1024 +
                             ((col * 2) ^ ((row0 & 15) << 4))) = (unsigned short)w;
          int row1 = row0 + 1;
          *(unsigned short*)(smem + HO + row1 * 1024 +
                             ((col * 2) ^ ((row1 & 15) << 4))) = (unsigned short)(w >> 16);
        }
      }
      acc0 = (f32x4){0.f, 0.f, 0.f, 0.f};
      acc1 = (f32x4){0.f, 0.f, 0.f, 0.f};
    }
    if (s == 7) LGKM_BAR();                    // publish H cols 0..255
    if (s == 15) {
      LGKM_BAR();                              // publish H cols 256..511; SPO free
      // x_eq -> SPO (bf16), via ds_write (no vmcnt impact)
      unsigned xw0 = cvtpk(xa[0], xa[1]);
      unsigned xw1 = cvtpk(xbv[0], xbv[1]);
      unsigned xw2 = cvtpk(xc[0], xc[1]);
      const int xb = srow * 192 + sj * 12;
      *(unsigned*)(smem + SPO + xb + 0) = xw0;
      *(unsigned*)(smem + SPO + xb + 4) = xw1;
      *(unsigned*)(smem + SPO + xb + 8) = xw2;
    }
  }

  // ================= B phase: chunks 16..47 =============================
#pragma unroll
  for (int s = 16; s < 48; ++s) {
    const int t = s - 16, kk = t & 7, QQ = t >> 3;
    if (s + 2 <= 47) {
      LGKM0();                                 // ring-slot WAR guard
      gl_lds16(Wall + (size_t)(s + 2) * 4096 + wv * 512 + lane * 8,
               smem + RNG + ((s + 2) % 3) * 8192 + wv * 1024);
    }
    if (s <= 45) WAITV(2);
    else if (s == 46) WAITV(1);
    else WAITV(0);
    __builtin_amdgcn_s_setprio(1);
    {
      const int hb = 512 + kk * 64 + g * 16;
      bf16x8 h0 = *(const bf16x8*)(smem + hro0 + (hb ^ hx));
      bf16x8 h1 = *(const bf16x8*)(smem + hro1 + (hb ^ hx));
      bf16x8 b = *(const bf16x8*)(smem + RNG + (s % 3) * 8192 + woff + wslot);
      acc0 = MFMA(h0, b, acc0);
      acc1 = MFMA(h1, b, acc1);
    }
    __builtin_amdgcn_s_setprio(0);
    if (t >= 8) {                              // phase-C slice, prev quarter
      const int Qp = QQ - 1, il = kk;
      const int wmoff = (Qp & 1) ? WMB : WMA;
      unsigned short w = *(const unsigned short*)(
          smem + wmoff + nloc * 256 + (((il * 16 + q) * 2) ^ ((nloc & 7) << 5)));
      float wf = bf2f(w);
      const int xb = nloc * 192 + (Qp * 24 + il * 3) * 2;
      eq0 += bf2f(*(const unsigned short*)(smem + SPO + xb + 0)) * wf;
      eq1 += bf2f(*(const unsigned short*)(smem + SPO + xb + 2)) * wf;
      eq2 += bf2f(*(const unsigned short*)(smem + SPO + xb + 4)) * wf;
    }
    if (kk == 7) {                             // Wm quarter write
      const int wmoff = (QQ & 1) ? WMB : WMA;
      const int lc = wv * 16 + o;
#pragma unroll
      for (int mt = 0; mt < 2; ++mt) {
        f32x4 a = mt ? acc1 : acc0;
#pragma unroll
        for (int rp = 0; rp < 2; ++rp) {
          unsigned w = cvtpk(a[rp * 2] * inv16, a[rp * 2 + 1] * inv16);
          int n0 = mt * 16 + g * 4 + rp * 2;
          *(unsigned short*)(smem + wmoff + n0 * 256 +
                             ((lc * 2) ^ ((n0 & 7) << 5))) = (unsigned short)w;
          int n1 = n0 + 1;
          *(unsigned short*)(smem + wmoff + n1 * 256 +
                             ((lc * 2) ^ ((n1 & 7) << 5))) = (unsigned short)(w >> 16);
        }
      }
      acc0 = (f32x4){0.f, 0.f, 0.f, 0.f};
      acc1 = (f32x4){0.f, 0.f, 0.f, 0.f};
      LGKM_BAR();                              // publish Wm quarter
    }
  }

  // ---- epilogue: final quarter (Qp=3, in WMB) + all global stores ------
#pragma unroll
  for (int il = 0; il < 8; ++il) {
    unsigned short w = *(const unsigned short*)(
        smem + WMB + nloc * 256 + (((il * 16 + q) * 2) ^ ((nloc & 7) << 5)));
    float wf = bf2f(w);
    const int xb = nloc * 192 + (72 + il * 3) * 2;
    eq0 += bf2f(*(const unsigned short*)(smem + SPO + xb + 0)) * wf;
    eq1 += bf2f(*(const unsigned short*)(smem + SPO + xb + 2)) * wf;
    eq2 += bf2f(*(const unsigned short*)(smem + SPO + xb + 4)) * wf;
  }

#pragma unroll
  for (int r = 0; r < 4; ++r) {
    int node = base + mtw * 16 + g * 4 + r;
    out[(size_t)node * OUTC + ct * 16 + o] = acc2[r] * invm[r];
  }
  float* op = out + (size_t)(base + nloc) * OUTC + 64 + q * 3;
  op[0] = eq0 * sC;
  op[1] = eq1 * sC;
  op[2] = eq2 * sC;
}

// ---- launch ------------------------------------------------------------
extern "C" void kernel_launch(void* const* d_in, const int* in_sizes, int n_in,
                              void* d_out, int out_size, void* d_ws, size_t ws_size,
                              hipStream_t stream) {
  const float* feats = (const float*)d_in[0];
  const int* ei = (const int*)d_in[1];
  const float* invW1 = (const float*)d_in[2];
  const float* invW2 = (const float*)d_in[3];
  const float* wembW1 = (const float*)d_in[4];
  const float* wembW2 = (const float*)d_in[5];
  float* out = (float*)d_out;

  char* ws = (char*)d_ws;
  unsigned short* W1s = (unsigned short*)(ws);                    // 131072 B (chunks 0..15)
  unsigned short* W2w = (unsigned short*)(ws + 131072);           // 262144 B (chunks 16..47)
  unsigned short* W2i = (unsigned short*)(ws + 393216);           // 32768 B
  unsigned char* act  = (unsigned char*)(ws + 425984);            // 100096 B

  k_zero<<<98, 256, 0, stream>>>((unsigned int*)act, 25024);
  k_scatter<<<1563, 256, 0, stream>>>(ei, act);
  k_wprep<<<832, 256, 0, stream>>>(invW1, invW2, wembW1, wembW2, W1s, W2w, W2i);
  k_main<<<3125, 512, 0, stream>>>(feats, W1s, W2i, act, out);
}